// Round 1
// baseline (139.186 us; speedup 1.0000x reference)
//
#include <hip/hip_runtime.h>
#include <math.h>

// DSVF via exact time-domain IIR (mathematically equal to the reference's
// FFT overlap-add because the biquad's poles have radius <~0.8, so the
// impulse response is numerically dead after ~128 samples; see analysis).
//
// Blocked parallel scan: each thread produces OUT_BLK=128 outputs after a
// WARM=128-sample warm-up from zero state (state error ~ r^128 < 1e-13 rel).

#define N_PER_ROW (128 * 2048)      // 262144 samples per batch row
#define OUT_BLK 128                  // outputs per thread
#define WARM 128                     // warm-up samples per thread
#define BLKS_PER_ROW (N_PER_ROW / OUT_BLK)  // 2048
#define BATCH 64

__global__ __launch_bounds__(256) void dsvf_iir_kernel(
    const float* __restrict__ x,
    const float* __restrict__ g_p, const float* __restrict__ R_p,
    const float* __restrict__ mhp_p, const float* __restrict__ mbp_p,
    const float* __restrict__ mlp_p,
    float* __restrict__ out)
{
    const int tid = blockIdx.x * blockDim.x + threadIdx.x;
    const int row = tid / BLKS_PER_ROW;
    const int blk = tid - row * BLKS_PER_ROW;
    if (row >= BATCH) return;

    // --- biquad coefficients (identical math to reference, fp32) ---
    const float g = g_p[0], R = R_p[0];
    const float m_hp = mhp_p[0], m_bp = mbp_p[0], m_lp = mlp_p[0];
    const float sig = 1.0f / (1.0f + expf(-g));
    const float gt  = tanf(1.5707963267948966f * sig);   // tan(pi*sig/2)
    const float Rt  = log1pf(expf(R));                   // softplus
    const float g2  = gt * gt;
    const float b0 = g2 * m_lp + gt * m_bp + m_hp;
    const float b1 = 2.0f * g2 * m_lp - 2.0f * m_hp;
    const float b2 = g2 * m_lp - gt * m_bp + m_hp;
    const float a0 = g2 + 2.0f * Rt * gt + 1.0f;
    const float a1 = 2.0f * g2 - 2.0f;
    const float a2 = g2 - 2.0f * Rt * gt + 1.0f;
    const float inv_a0 = 1.0f / a0;
    const float B0 = b0 * inv_a0, B1 = b1 * inv_a0, B2 = b2 * inv_a0;
    const float A1 = a1 * inv_a0, A2 = a2 * inv_a0;

    const float* __restrict__ xr = x + (size_t)row * N_PER_ROW;
    float* __restrict__ yr = out + (size_t)row * N_PER_ROW;
    const int o0 = blk * OUT_BLK;

    // Direct-form II transposed state
    float s1 = 0.0f, s2 = 0.0f;

#define STEP_D(xx) { float y_ = fmaf(B0, (xx), s1);                 \
                     s1 = fmaf(-A1, y_, fmaf(B1, (xx), s2));        \
                     s2 = fmaf(-A2, y_, B2 * (xx)); }
#define STEP_S(xx, yy) { (yy) = fmaf(B0, (xx), s1);                 \
                     s1 = fmaf(-A1, (yy), fmaf(B1, (xx), s2));      \
                     s2 = fmaf(-A2, (yy), B2 * (xx)); }

    // Warm-up (discard outputs); first block of a row starts exactly at
    // zero state, matching the reference's zero-padded first segment.
    if (blk > 0) {
        const float4* wp = (const float4*)(xr + o0 - WARM);
        #pragma unroll 8
        for (int i = 0; i < WARM / 4; ++i) {
            float4 v = wp[i];
            STEP_D(v.x); STEP_D(v.y); STEP_D(v.z); STEP_D(v.w);
        }
    }

    // Emit OUT_BLK outputs, float4-vectorized load and store.
    const float4* ip = (const float4*)(xr + o0);
    float4* op = (float4*)(yr + o0);
    #pragma unroll 8
    for (int i = 0; i < OUT_BLK / 4; ++i) {
        float4 v = ip[i];
        float4 o;
        STEP_S(v.x, o.x); STEP_S(v.y, o.y); STEP_S(v.z, o.z); STEP_S(v.w, o.w);
        op[i] = o;
    }
#undef STEP_D
#undef STEP_S
}

extern "C" void kernel_launch(void* const* d_in, const int* in_sizes, int n_in,
                              void* d_out, int out_size, void* d_ws, size_t ws_size,
                              hipStream_t stream) {
    const float* x    = (const float*)d_in[0];
    const float* g    = (const float*)d_in[1];
    const float* R    = (const float*)d_in[2];
    const float* m_hp = (const float*)d_in[3];
    const float* m_bp = (const float*)d_in[4];
    const float* m_lp = (const float*)d_in[5];
    float* out = (float*)d_out;

    const int total_threads = BATCH * BLKS_PER_ROW;   // 131072
    dim3 block(256);
    dim3 grid(total_threads / 256);                   // 512 blocks
    dsvf_iir_kernel<<<grid, block, 0, stream>>>(x, g, R, m_hp, m_bp, m_lp, out);
}